// Round 5
// baseline (233.446 us; speedup 1.0000x reference)
//
#include <hip/hip_runtime.h>

typedef short v8s __attribute__((ext_vector_type(8)));
typedef float v4f __attribute__((ext_vector_type(4)));

#define Wh   1024
#define Hh   512
#define HWh  (Wh * Hh)
#define Wlr  512
#define HWlr (Wlr * 256)

#define THREADS 512
#define WAVES   8
#define PXW     32        // pixels per wave-iteration (two 16-px MFMA N-tiles)
#define NBLK    256
#define ITERS   8         // 256 blk * 8 waves * 8 iters * 32 px = 524288

// Activation buffers: fragment-major (B-operand layout), element (px, ch) at
//   half = px>>4, frag = ch>>5, lane' = ((ch>>3)&3)*16 + (px&15), offset = ch&7
// half stride padded +4 shorts so the two halves' staging writes hit disjoint banks.
#define HALF_STRIDE 2052              // 4 frags * 512 + 4 pad (shorts)
#define BUF_STRIDE  (2 * HALF_STRIDE) // one ping-pong buffer (shorts)
#define ACT_SHORTS  (2 * BUF_STRIDE)  // two buffers per wave = 8208 shorts
#define WF_N        21                // W1:16 frags, W2:4, W3:1
#define WFRAG_SHORTS (WF_N * 512)
#define LDS_BYTES   ((WFRAG_SHORTS + WAVES * ACT_SHORTS) * 2)  // 21504 + 131328 = 152832

__device__ __forceinline__ unsigned short f2bf(float f) {
    union { float f; unsigned u; } v; v.f = f;
    unsigned r = v.u + 0x7FFFu + ((v.u >> 16) & 1u);  // RNE (cold paths only)
    return (unsigned short)(r >> 16);
}
// hot-path pack: round-half-up bias + v_perm grabbing the two high halves (3 VALU)
__device__ __forceinline__ unsigned pk2(float a, float b) {
    union { float f; unsigned u; } ua, ub;
    ua.f = a; ub.f = b;
    return __builtin_amdgcn_perm(ub.u + 0x8000u, ua.u + 0x8000u, 0x07060302u);
}
__device__ __forceinline__ float leaky(float x) { return fmaxf(x, 0.01f * x); }

// epilogue write: 4 consecutive channels c0..c0+3 (c0 = c0base + 4q) of pixel p, half h
__device__ __forceinline__ void ep_write(unsigned short* buf, int h, int c0, int p, uint2 v) {
    *(uint2*)(buf + h * HALF_STRIDE + (c0 >> 5) * 512 + (((c0 >> 3) & 3) * 16 + p) * 8 + (c0 & 7)) = v;
}
// staging write: channel pair (rc, rc+1) of pixel px into buf
__device__ __forceinline__ void stage_pair(unsigned short* buf, int px, int rc, unsigned v) {
    *(unsigned*)(buf + (px >> 4) * HALF_STRIDE + (rc >> 5) * 512 +
                 (((rc >> 3) & 3) * 16 + (px & 15)) * 8 + (rc & 7)) = v;
}

__global__ __launch_bounds__(THREADS, 2)
void cmfsm_kernel(const float* __restrict__ lr, const float* __restrict__ hr,
                  const float* __restrict__ w0g, const float* __restrict__ w1g,
                  const float* __restrict__ w2g, const float* __restrict__ w3g,
                  const float* __restrict__ w4g, const float* __restrict__ w5g,
                  const float* __restrict__ t0g, const float* __restrict__ t1g,
                  const float* __restrict__ t2g, const float* __restrict__ fwg,
                  float* __restrict__ out)
{
    extern __shared__ unsigned short smem[];
    unsigned short* wfrag = smem;                    // W1..W3 fragments
    unsigned short* actS  = smem + WFRAG_SHORTS;

    const int tid  = threadIdx.x;
    const int lane = tid & 63;
    const int wv   = tid >> 6;
    const int p    = lane & 15;   // MFMA n within a 16-px tile
    const int q    = lane >> 4;   // MFMA k-quad
    const int px   = lane & 31;   // staging pixel
    const int cp   = lane >> 5;   // staging channel-pair selector

    // ---- stage W1 (frags 0..15), W2 (16..19), W3 (20) as lane-contiguous A-frags ----
    for (int e = tid; e < 16 * 64; e += THREADS) {
        int f = e >> 6, l = e & 63;
        int mt = f >> 2, ks = f & 3, pp = l & 15, qq = l >> 4;
        const float* src = w1g + (mt * 16 + pp) * 128 + ks * 32 + qq * 8;
        unsigned short* dst = wfrag + f * 512 + l * 8;
#pragma unroll
        for (int j = 0; j < 8; ++j) dst[j] = f2bf(src[j]);
    }
    if (tid < 4 * 64) {
        int f = tid >> 6, l = tid & 63;
        int mt = f >> 1, ks = f & 1, pp = l & 15, qq = l >> 4;
        const float* src = w2g + (mt * 16 + pp) * 64 + ks * 32 + qq * 8;
        unsigned short* dst = wfrag + (16 + f) * 512 + l * 8;
#pragma unroll
        for (int j = 0; j < 8; ++j) dst[j] = f2bf(src[j]);
    }
    if (tid < 64) {
        int l = tid, pp = l & 15, qq = l >> 4;
        const float* src = w3g + pp * 32 + qq * 8;
        unsigned short* dst = wfrag + 20 * 512 + l * 8;
#pragma unroll
        for (int j = 0; j < 8; ++j) dst[j] = f2bf(src[j]);
    }

    // ---- W0 A-fragments in registers: w0f[mt*4+ks] = A[16mt+p][32ks+8q+j] ----
    v8s w0f[32];
#pragma unroll
    for (int f = 0; f < 32; ++f) {
        int mt = f >> 2, ks = f & 3;
        const float* src = w0g + (mt * 16 + p) * 128 + ks * 32 + q * 8;
        v8s t;
#pragma unroll
        for (int j = 0; j < 8; ++j) t[j] = (short)f2bf(src[j]);
        w0f[f] = t;
    }

    // ---- fused layers 4+5: w45[r] = sum_j w5[j]*w4[j][4q+r] ----
    float w45[4];
#pragma unroll
    for (int r = 0; r < 4; ++r) {
        float s = 0.f;
#pragma unroll
        for (int j = 0; j < 8; ++j) s += w5g[j] * w4g[j * 16 + q * 4 + r];
        w45[r] = s;
    }

    // ---- weights2: 4 parity values ----
    float w2tab[4];
#pragma unroll
    for (int yp = 0; yp < 2; ++yp)
#pragma unroll
        for (int xp = 0; xp < 2; ++xp) {
            float i0 = xp ? 1.f : -1.f;
            float i1 = yp ? 1.f : -1.f;
            float i2 = 1.41421356237309505f;
            float h0[3], h1[2];
            for (int o = 0; o < 3; ++o)
                h0[o] = leaky(t0g[o*3+0]*i0 + t0g[o*3+1]*i1 + t0g[o*3+2]*i2);
            for (int o = 0; o < 2; ++o)
                h1[o] = leaky(t1g[o*3+0]*h0[0] + t1g[o*3+1]*h0[1] + t1g[o*3+2]*h0[2]);
            w2tab[yp*2+xp] = t2g[0]*h1[0] + t2g[1]*h1[1];
        }
    const float fa = fabsf(fwg[0]);
    const float fb = fabsf(fwg[1]);

    __syncthreads();   // wfrag ready; act buffers are wave-private hereafter

    unsigned short* actW = actS + wv * ACT_SHORTS;
    unsigned short* B0 = actW;               // buffer 0 (rep / layer1-out)
    unsigned short* B1 = actW + BUF_STRIDE;  // buffer 1 (layer0-out / layer2-out)
    const v4f z4 = (v4f){0.f, 0.f, 0.f, 0.f};

    for (int it = 0; it < ITERS; ++it) {
        const int gbase = ((blockIdx.x * ITERS + it) * WAVES + wv) * PXW;  // wave-uniform
        const int y     = gbase >> 10;
        const int x0    = gbase & 1023;
        const float* hr_it = hr + gbase;                       // + ch*HWh + px
        const float* lr_it = lr + (y >> 1) * Wlr + (x0 >> 1);  // + ch*HWlr + (px>>1)

        // ---- stage rep into B0: 8 passes, each lane 2 consecutive channels of 1 px ----
#pragma unroll
        for (int pass = 0; pass < 8; ++pass) {
            const int ch = pass * 4 + cp * 2;
            float h0 = hr_it[(size_t)ch * HWh + px];
            float h1 = hr_it[(size_t)(ch + 1) * HWh + px];
            float l0 = lr_it[(size_t)ch * HWlr + (px >> 1)];
            float l1 = lr_it[(size_t)(ch + 1) * HWlr + (px >> 1)];
            stage_pair(B0, px, ch,      pk2(l0, l1));            // lr_up
            stage_pair(B0, px, 32 + ch, pk2(h0, h1));            // hr
            stage_pair(B0, px, 64 + ch, pk2(l0 * h0, l1 * h1));  // product
            float d0 = l0 - h0, d1 = l1 - h1;
            stage_pair(B0, px, 96 + ch, pk2(d0 * d0, d1 * d1));  // squared diff
        }

        // ---- layer 0: 128 -> 128, W0 from regs, two mt-halves, out -> B1 ----
#pragma unroll
        for (int mh = 0; mh < 2; ++mh) {
            v4f acc[4][2];
#pragma unroll
            for (int ks = 0; ks < 4; ++ks) {
                v8s b0 = *(const v8s*)(B0 + ks * 512 + lane * 8);
                v8s b1 = *(const v8s*)(B0 + HALF_STRIDE + ks * 512 + lane * 8);
#pragma unroll
                for (int mi = 0; mi < 4; ++mi) {
                    const int f = (mh * 4 + mi) * 4 + ks;
                    acc[mi][0] = __builtin_amdgcn_mfma_f32_16x16x32_bf16(
                        w0f[f], b0, ks == 0 ? z4 : acc[mi][0], 0, 0, 0);
                    acc[mi][1] = __builtin_amdgcn_mfma_f32_16x16x32_bf16(
                        w0f[f], b1, ks == 0 ? z4 : acc[mi][1], 0, 0, 0);
                }
            }
#pragma unroll
            for (int mi = 0; mi < 4; ++mi) {
                const int c0 = 16 * (mh * 4 + mi) + 4 * q;
#pragma unroll
                for (int h = 0; h < 2; ++h) {
                    uint2 v;
                    v.x = pk2(leaky(acc[mi][h][0]), leaky(acc[mi][h][1]));
                    v.y = pk2(leaky(acc[mi][h][2]), leaky(acc[mi][h][3]));
                    ep_write(B1, h, c0, p, v);
                }
            }
        }

        // ---- layer 1: 128 -> 64, W1 from LDS, reads B1, out -> B0 ----
        {
            v4f acc[4][2];
#pragma unroll
            for (int ks = 0; ks < 4; ++ks) {
                v8s b0 = *(const v8s*)(B1 + ks * 512 + lane * 8);
                v8s b1 = *(const v8s*)(B1 + HALF_STRIDE + ks * 512 + lane * 8);
#pragma unroll
                for (int mt = 0; mt < 4; ++mt) {
                    v8s a = *(const v8s*)(wfrag + (mt * 4 + ks) * 512 + lane * 8);
                    acc[mt][0] = __builtin_amdgcn_mfma_f32_16x16x32_bf16(
                        a, b0, ks == 0 ? z4 : acc[mt][0], 0, 0, 0);
                    acc[mt][1] = __builtin_amdgcn_mfma_f32_16x16x32_bf16(
                        a, b1, ks == 0 ? z4 : acc[mt][1], 0, 0, 0);
                }
            }
#pragma unroll
            for (int mt = 0; mt < 4; ++mt) {
                const int c0 = 16 * mt + 4 * q;
#pragma unroll
                for (int h = 0; h < 2; ++h) {
                    uint2 v;
                    v.x = pk2(leaky(acc[mt][h][0]), leaky(acc[mt][h][1]));
                    v.y = pk2(leaky(acc[mt][h][2]), leaky(acc[mt][h][3]));
                    ep_write(B0, h, c0, p, v);
                }
            }
        }

        // ---- layer 2: 64 -> 32, W2 from LDS, reads B0 frags 0..1, out -> B1 frag 0 ----
        {
            v4f acc[2][2];
#pragma unroll
            for (int ks = 0; ks < 2; ++ks) {
                v8s b0 = *(const v8s*)(B0 + ks * 512 + lane * 8);
                v8s b1 = *(const v8s*)(B0 + HALF_STRIDE + ks * 512 + lane * 8);
#pragma unroll
                for (int mt = 0; mt < 2; ++mt) {
                    v8s a = *(const v8s*)(wfrag + (16 + mt * 2 + ks) * 512 + lane * 8);
                    acc[mt][0] = __builtin_amdgcn_mfma_f32_16x16x32_bf16(
                        a, b0, ks == 0 ? z4 : acc[mt][0], 0, 0, 0);
                    acc[mt][1] = __builtin_amdgcn_mfma_f32_16x16x32_bf16(
                        a, b1, ks == 0 ? z4 : acc[mt][1], 0, 0, 0);
                }
            }
#pragma unroll
            for (int mt = 0; mt < 2; ++mt) {
                const int c0 = 16 * mt + 4 * q;
#pragma unroll
                for (int h = 0; h < 2; ++h) {
                    uint2 v;
                    v.x = pk2(leaky(acc[mt][h][0]), leaky(acc[mt][h][1]));
                    v.y = pk2(leaky(acc[mt][h][2]), leaky(acc[mt][h][3]));
                    ep_write(B1, h, c0, p, v);
                }
            }
        }

        // ---- layer 3: 32 -> 16, fused 16->8->1, fuse with weights2 ----
        {
            v8s a = *(const v8s*)(wfrag + 20 * 512 + lane * 8);
            float res[2];
#pragma unroll
            for (int h = 0; h < 2; ++h) {
                v8s b = *(const v8s*)(B1 + h * HALF_STRIDE + lane * 8);
                v4f acc3 = __builtin_amdgcn_mfma_f32_16x16x32_bf16(a, b, z4, 0, 0, 0);
                float part = 0.f;
#pragma unroll
                for (int r = 0; r < 4; ++r) part += w45[r] * leaky(acc3[r]);
                part += __shfl_xor(part, 16, 64);
                part += __shfl_xor(part, 32, 64);
                res[h] = part;
            }
            const float wb = fb * w2tab[((y & 1) << 1) | (p & 1)];
            if (q == 0)      out[gbase + p]      = fa * res[0] + wb;
            else if (q == 1) out[gbase + 16 + p] = fa * res[1] + wb;
        }
    }
}

extern "C" void kernel_launch(void* const* d_in, const int* in_sizes, int n_in,
                              void* d_out, int out_size, void* d_ws, size_t ws_size,
                              hipStream_t stream) {
    const float* lr  = (const float*)d_in[0];
    const float* hr  = (const float*)d_in[1];
    const float* w0g = (const float*)d_in[2];
    const float* w1g = (const float*)d_in[3];
    const float* w2g = (const float*)d_in[4];
    const float* w3g = (const float*)d_in[5];
    const float* w4g = (const float*)d_in[6];
    const float* w5g = (const float*)d_in[7];
    const float* t0g = (const float*)d_in[8];
    const float* t1g = (const float*)d_in[9];
    const float* t2g = (const float*)d_in[10];
    const float* fwg = (const float*)d_in[11];
    float* out = (float*)d_out;

    hipLaunchKernelGGL(cmfsm_kernel, dim3(NBLK), dim3(THREADS), LDS_BYTES, stream,
                       lr, hr, w0g, w1g, w2g, w3g, w4g, w5g, t0g, t1g, t2g, fwg, out);
}

// Round 6
// 165.700 us; speedup vs baseline: 1.4088x; 1.4088x over previous
//
#include <hip/hip_runtime.h>

typedef short v8s __attribute__((ext_vector_type(8)));
typedef float v4f __attribute__((ext_vector_type(4)));

#define Wh   1024
#define HWh  (1024 * 512)
#define Wlr  512
#define HWlr (512 * 256)

#define THREADS 768
#define WAVES   12
#define NBLK    256
#define SLOTS   64        // 32-px wave-iterations per block (64*32 = 2048 px = 2 rows)
#define MAXIT   6         // ceil(64/12)

// Activation buffer: fragment-major B-operand layout, in-place, wave-private.
// element (px, ch): half = px>>4, frag = ch>>5, lane' = ((ch>>3)&3)*16 + (px&15), off = ch&7
#define HALF_STRIDE 2052               // 4 frags * 512 + 4 pad (shorts)
#define ACT_SHORTS  (2 * HALF_STRIDE)  // 4104 shorts = 8208 B per wave
#define WF_N         53                // W0:32 frags, W1:16, W2:4, W3:1
#define WFRAG_SHORTS (WF_N * 512)
#define LDS_BYTES   ((WFRAG_SHORTS + WAVES * ACT_SHORTS) * 2)  // 152768 B

__device__ __forceinline__ unsigned short f2bf(float f) {
    union { float f; unsigned u; } v; v.f = f;
    unsigned r = v.u + 0x7FFFu + ((v.u >> 16) & 1u);  // RNE (cold paths only)
    return (unsigned short)(r >> 16);
}
// hot-path pack: round-half-up bias + v_perm grabbing the two high halves (3 VALU)
__device__ __forceinline__ unsigned pk2(float a, float b) {
    union { float f; unsigned u; } ua, ub;
    ua.f = a; ub.f = b;
    return __builtin_amdgcn_perm(ub.u + 0x8000u, ua.u + 0x8000u, 0x07060302u);
}
__device__ __forceinline__ float leaky(float x) { return fmaxf(x, 0.01f * x); }

// epilogue write: channels c0..c0+3 (c0 = 16*mt + 4*q) of pixel p, half h
__device__ __forceinline__ void ep_write(unsigned short* buf, int h, int c0, int p, uint2 v) {
    *(uint2*)(buf + h * HALF_STRIDE + (c0 >> 5) * 512 +
              (((c0 >> 3) & 3) * 16 + p) * 8 + (c0 & 7)) = v;
}
// staging write: rep component c (frag c), channels 8*pass+4*cq .. +3, pixel px
__device__ __forceinline__ void stq(unsigned short* buf, int px, int pass, int cq,
                                    int c, unsigned lo, unsigned hi) {
    *(uint2*)(buf + (px >> 4) * HALF_STRIDE + c * 512 +
              (pass * 16 + (px & 15)) * 8 + 4 * cq) = (uint2){lo, hi};
}

__global__ __launch_bounds__(THREADS, 3)
void cmfsm_kernel(const float* __restrict__ lr, const float* __restrict__ hr,
                  const float* __restrict__ w0g, const float* __restrict__ w1g,
                  const float* __restrict__ w2g, const float* __restrict__ w3g,
                  const float* __restrict__ w4g, const float* __restrict__ w5g,
                  const float* __restrict__ t0g, const float* __restrict__ t1g,
                  const float* __restrict__ t2g, const float* __restrict__ fwg,
                  float* __restrict__ out)
{
    extern __shared__ unsigned short smem[];
    unsigned short* wfrag = smem;                    // 53 lane-contiguous A-fragments
    unsigned short* actS  = smem + WFRAG_SHORTS;

    const int tid  = threadIdx.x;
    const int lane = tid & 63;
    const int wv   = tid >> 6;
    const int p    = lane & 15;   // MFMA n within a 16-px tile
    const int q    = lane >> 4;   // MFMA k-quad
    const int px   = lane & 31;   // staging pixel
    const int cq   = lane >> 5;   // staging channel-quad selector

    // ---- stage weights as A-fragments (frag idx: W0 0..31, W1 32..47, W2 48..51, W3 52) ----
    for (int e = tid; e < 32 * 64; e += THREADS) {
        int f = e >> 6, l = e & 63;
        int mt = f >> 2, ks = f & 3, pp = l & 15, qq = l >> 4;
        const float* src = w0g + (mt * 16 + pp) * 128 + ks * 32 + qq * 8;
        unsigned short* dst = wfrag + f * 512 + l * 8;
#pragma unroll
        for (int j = 0; j < 8; ++j) dst[j] = f2bf(src[j]);
    }
    for (int e = tid; e < 16 * 64; e += THREADS) {
        int f = e >> 6, l = e & 63;
        int mt = f >> 2, ks = f & 3, pp = l & 15, qq = l >> 4;
        const float* src = w1g + (mt * 16 + pp) * 128 + ks * 32 + qq * 8;
        unsigned short* dst = wfrag + (32 + f) * 512 + l * 8;
#pragma unroll
        for (int j = 0; j < 8; ++j) dst[j] = f2bf(src[j]);
    }
    if (tid < 4 * 64) {
        int f = tid >> 6, l = tid & 63;
        int mt = f >> 1, ks = f & 1, pp = l & 15, qq = l >> 4;
        const float* src = w2g + (mt * 16 + pp) * 64 + ks * 32 + qq * 8;
        unsigned short* dst = wfrag + (48 + f) * 512 + l * 8;
#pragma unroll
        for (int j = 0; j < 8; ++j) dst[j] = f2bf(src[j]);
    }
    if (tid < 64) {
        int l = tid, pp = l & 15, qq = l >> 4;
        const float* src = w3g + pp * 32 + qq * 8;
        unsigned short* dst = wfrag + 52 * 512 + l * 8;
#pragma unroll
        for (int j = 0; j < 8; ++j) dst[j] = f2bf(src[j]);
    }

    // ---- fused layers 4+5: w45[r] = sum_j w5[j]*w4[j][4q+r] ----
    float w45[4];
#pragma unroll
    for (int r = 0; r < 4; ++r) {
        float s = 0.f;
#pragma unroll
        for (int j = 0; j < 8; ++j) s += w5g[j] * w4g[j * 16 + q * 4 + r];
        w45[r] = s;
    }

    // ---- weights2: 4 parity values ----
    float w2tab[4];
#pragma unroll
    for (int yp = 0; yp < 2; ++yp)
#pragma unroll
        for (int xp = 0; xp < 2; ++xp) {
            float i0 = xp ? 1.f : -1.f;
            float i1 = yp ? 1.f : -1.f;
            float i2 = 1.41421356237309505f;
            float h0[3], h1[2];
            for (int o = 0; o < 3; ++o)
                h0[o] = leaky(t0g[o*3+0]*i0 + t0g[o*3+1]*i1 + t0g[o*3+2]*i2);
            for (int o = 0; o < 2; ++o)
                h1[o] = leaky(t1g[o*3+0]*h0[0] + t1g[o*3+1]*h0[1] + t1g[o*3+2]*h0[2]);
            w2tab[yp*2+xp] = t2g[0]*h1[0] + t2g[1]*h1[1];
        }
    const float fa = fabsf(fwg[0]);
    const float fb = fabsf(fwg[1]);

    __syncthreads();   // wfrag ready; act buffers are wave-private hereafter

    unsigned short* B = actS + wv * ACT_SHORTS;
    const v4f z4 = (v4f){0.f, 0.f, 0.f, 0.f};

    for (int it = 0; it < MAXIT; ++it) {
        const int s = it * WAVES + wv;
        if (s >= SLOTS) break;
        const int gbase = (blockIdx.x * SLOTS + s) * 32;   // wave-uniform, 32 px one row
        const int y     = gbase >> 10;
        const float* hr_it = hr + gbase;                        // + ch*HWh + px
        const float* lr_it = lr + (y >> 1) * Wlr + ((gbase & 1023) >> 1);

        // ---- stage rep: 4 passes, each lane 4 consecutive channels of 1 px (b64 writes) ----
#pragma unroll
        for (int pass = 0; pass < 4; ++pass) {
            const int ch = pass * 8 + cq * 4;
            float h0 = hr_it[(size_t)(ch + 0) * HWh + px];
            float h1 = hr_it[(size_t)(ch + 1) * HWh + px];
            float h2 = hr_it[(size_t)(ch + 2) * HWh + px];
            float h3 = hr_it[(size_t)(ch + 3) * HWh + px];
            float l0 = lr_it[(size_t)(ch + 0) * HWlr + (px >> 1)];
            float l1 = lr_it[(size_t)(ch + 1) * HWlr + (px >> 1)];
            float l2 = lr_it[(size_t)(ch + 2) * HWlr + (px >> 1)];
            float l3 = lr_it[(size_t)(ch + 3) * HWlr + (px >> 1)];
            stq(B, px, pass, cq, 0, pk2(l0, l1), pk2(l2, l3));                  // lr_up
            stq(B, px, pass, cq, 1, pk2(h0, h1), pk2(h2, h3));                  // hr
            stq(B, px, pass, cq, 2, pk2(l0*h0, l1*h1), pk2(l2*h2, l3*h3));      // product
            float d0 = l0-h0, d1 = l1-h1, d2 = l2-h2, d3 = l3-h3;
            stq(B, px, pass, cq, 3, pk2(d0*d0, d1*d1), pk2(d2*d2, d3*d3));      // sq diff
        }

        // ---- layer 0: 128 -> 128, b-frags cached in regs (in-place safe) ----
        {
            v8s bfr[4][2];
#pragma unroll
            for (int ks = 0; ks < 4; ++ks) {
                bfr[ks][0] = *(const v8s*)(B + ks * 512 + lane * 8);
                bfr[ks][1] = *(const v8s*)(B + HALF_STRIDE + ks * 512 + lane * 8);
            }
#pragma unroll
            for (int mh = 0; mh < 2; ++mh) {
                v4f acc[4][2];
#pragma unroll
                for (int ks = 0; ks < 4; ++ks)
#pragma unroll
                    for (int mi = 0; mi < 4; ++mi) {
                        v8s a = *(const v8s*)(wfrag + ((mh*4+mi)*4 + ks) * 512 + lane * 8);
                        acc[mi][0] = __builtin_amdgcn_mfma_f32_16x16x32_bf16(
                            a, bfr[ks][0], ks == 0 ? z4 : acc[mi][0], 0, 0, 0);
                        acc[mi][1] = __builtin_amdgcn_mfma_f32_16x16x32_bf16(
                            a, bfr[ks][1], ks == 0 ? z4 : acc[mi][1], 0, 0, 0);
                    }
#pragma unroll
                for (int mi = 0; mi < 4; ++mi) {
                    const int c0 = 16 * (mh * 4 + mi) + 4 * q;
#pragma unroll
                    for (int h = 0; h < 2; ++h) {
                        uint2 v;
                        v.x = pk2(leaky(acc[mi][h][0]), leaky(acc[mi][h][1]));
                        v.y = pk2(leaky(acc[mi][h][2]), leaky(acc[mi][h][3]));
                        ep_write(B, h, c0, p, v);
                    }
                }
            }
        }

        // ---- layer 1: 128 -> 64 ----
        {
            v8s bfr[4][2];
#pragma unroll
            for (int ks = 0; ks < 4; ++ks) {
                bfr[ks][0] = *(const v8s*)(B + ks * 512 + lane * 8);
                bfr[ks][1] = *(const v8s*)(B + HALF_STRIDE + ks * 512 + lane * 8);
            }
            v4f acc[4][2];
#pragma unroll
            for (int ks = 0; ks < 4; ++ks)
#pragma unroll
                for (int mt = 0; mt < 4; ++mt) {
                    v8s a = *(const v8s*)(wfrag + (32 + mt*4 + ks) * 512 + lane * 8);
                    acc[mt][0] = __builtin_amdgcn_mfma_f32_16x16x32_bf16(
                        a, bfr[ks][0], ks == 0 ? z4 : acc[mt][0], 0, 0, 0);
                    acc[mt][1] = __builtin_amdgcn_mfma_f32_16x16x32_bf16(
                        a, bfr[ks][1], ks == 0 ? z4 : acc[mt][1], 0, 0, 0);
                }
#pragma unroll
            for (int mt = 0; mt < 4; ++mt) {
                const int c0 = 16 * mt + 4 * q;
#pragma unroll
                for (int h = 0; h < 2; ++h) {
                    uint2 v;
                    v.x = pk2(leaky(acc[mt][h][0]), leaky(acc[mt][h][1]));
                    v.y = pk2(leaky(acc[mt][h][2]), leaky(acc[mt][h][3]));
                    ep_write(B, h, c0, p, v);
                }
            }
        }

        // ---- layer 2: 64 -> 32 ----
        {
            v8s bfr[2][2];
#pragma unroll
            for (int ks = 0; ks < 2; ++ks) {
                bfr[ks][0] = *(const v8s*)(B + ks * 512 + lane * 8);
                bfr[ks][1] = *(const v8s*)(B + HALF_STRIDE + ks * 512 + lane * 8);
            }
            v4f acc[2][2];
#pragma unroll
            for (int ks = 0; ks < 2; ++ks)
#pragma unroll
                for (int mt = 0; mt < 2; ++mt) {
                    v8s a = *(const v8s*)(wfrag + (48 + mt*2 + ks) * 512 + lane * 8);
                    acc[mt][0] = __builtin_amdgcn_mfma_f32_16x16x32_bf16(
                        a, bfr[ks][0], ks == 0 ? z4 : acc[mt][0], 0, 0, 0);
                    acc[mt][1] = __builtin_amdgcn_mfma_f32_16x16x32_bf16(
                        a, bfr[ks][1], ks == 0 ? z4 : acc[mt][1], 0, 0, 0);
                }
#pragma unroll
            for (int mt = 0; mt < 2; ++mt) {
                const int c0 = 16 * mt + 4 * q;
#pragma unroll
                for (int h = 0; h < 2; ++h) {
                    uint2 v;
                    v.x = pk2(leaky(acc[mt][h][0]), leaky(acc[mt][h][1]));
                    v.y = pk2(leaky(acc[mt][h][2]), leaky(acc[mt][h][3]));
                    ep_write(B, h, c0, p, v);
                }
            }
        }

        // ---- layer 3: 32 -> 16, fused 16->8->1, fuse with weights2 ----
        {
            v8s a = *(const v8s*)(wfrag + 52 * 512 + lane * 8);
            float res[2];
#pragma unroll
            for (int h = 0; h < 2; ++h) {
                v8s b = *(const v8s*)(B + h * HALF_STRIDE + lane * 8);
                v4f acc3 = __builtin_amdgcn_mfma_f32_16x16x32_bf16(a, b, z4, 0, 0, 0);
                float part = 0.f;
#pragma unroll
                for (int r = 0; r < 4; ++r) part += w45[r] * leaky(acc3[r]);
                part += __shfl_xor(part, 16, 64);
                part += __shfl_xor(part, 32, 64);
                res[h] = part;
            }
            const float wb = fb * w2tab[((y & 1) << 1) | (p & 1)];
            if (q == 0)      out[gbase + p]      = fa * res[0] + wb;
            else if (q == 1) out[gbase + 16 + p] = fa * res[1] + wb;
        }
    }
}

extern "C" void kernel_launch(void* const* d_in, const int* in_sizes, int n_in,
                              void* d_out, int out_size, void* d_ws, size_t ws_size,
                              hipStream_t stream) {
    const float* lr  = (const float*)d_in[0];
    const float* hr  = (const float*)d_in[1];
    const float* w0g = (const float*)d_in[2];
    const float* w1g = (const float*)d_in[3];
    const float* w2g = (const float*)d_in[4];
    const float* w3g = (const float*)d_in[5];
    const float* w4g = (const float*)d_in[6];
    const float* w5g = (const float*)d_in[7];
    const float* t0g = (const float*)d_in[8];
    const float* t1g = (const float*)d_in[9];
    const float* t2g = (const float*)d_in[10];
    const float* fwg = (const float*)d_in[11];
    float* out = (float*)d_out;

    hipLaunchKernelGGL(cmfsm_kernel, dim3(NBLK), dim3(THREADS), LDS_BYTES, stream,
                       lr, hr, w0g, w1g, w2g, w3g, w4g, w5g, t0g, t1g, t2g, fwg, out);
}